// Round 1
// baseline (286.579 us; speedup 1.0000x reference)
//
#include <hip/hip_runtime.h>
#include <hip/hip_bf16.h>

// MoE top-1: N=16384 tokens, D=1024, E=8 experts.
// out[n] = expert_w[argmax(router(x[n]))] @ x[n] + expert_b[e]
//
// Pipeline: init counts -> convert W to bf16 -> router (f64 logits, argmax,
// build per-expert token lists, fused x->bf16) -> grouped bf16-MFMA GEMM.

#define NTOK 16384
#define DIM  1024
#define NEXP 8

typedef __bf16 bf16x8 __attribute__((ext_vector_type(8)));
typedef float  f32x4  __attribute__((ext_vector_type(4)));

__device__ __forceinline__ unsigned short f2bf(float f) {
  unsigned int u = __builtin_bit_cast(unsigned int, f);
  u += 0x7FFFu + ((u >> 16) & 1u);   // round-to-nearest-even (finite inputs)
  return (unsigned short)(u >> 16);
}

__global__ __launch_bounds__(64) void k_init(int* counts) {
  if (threadIdx.x < NEXP) counts[threadIdx.x] = 0;
}

// expert_w f32 -> bf16, 8 elements per thread. grid 4096 x 256.
__global__ __launch_bounds__(256) void k_convw(const float* __restrict__ src,
                                               unsigned short* __restrict__ dst) {
  size_t i = ((size_t)blockIdx.x * 256 + threadIdx.x) * 8;
  const float4* p = (const float4*)(src + i);
  float4 a = p[0], b = p[1];
  unsigned int w0 = (unsigned)f2bf(a.x) | ((unsigned)f2bf(a.y) << 16);
  unsigned int w1 = (unsigned)f2bf(a.z) | ((unsigned)f2bf(a.w) << 16);
  unsigned int w2 = (unsigned)f2bf(b.x) | ((unsigned)f2bf(b.y) << 16);
  unsigned int w3 = (unsigned)f2bf(b.z) | ((unsigned)f2bf(b.w) << 16);
  *(uint4*)(dst + i) = make_uint4(w0, w1, w2, w3);
}

// Router: one wave per token. f64 accumulation so argmax matches exact logits.
// Also converts x to bf16 (x is being read anyway).
__global__ __launch_bounds__(256) void k_router(const float* __restrict__ x,
                                                const float* __restrict__ rw,
                                                const float* __restrict__ rb,
                                                unsigned short* __restrict__ xbf,
                                                int* __restrict__ counts,
                                                int* __restrict__ tok) {
  const int lane = threadIdx.x & 63;
  const int wave = threadIdx.x >> 6;
  const int n = (blockIdx.x << 2) + wave;

  const float4* xp = (const float4*)(x + (size_t)n * DIM + lane * 16);
  float v[16];
#pragma unroll
  for (int i = 0; i < 4; ++i) *(float4*)&v[i * 4] = xp[i];

  // fused bf16 conversion + store (32 B/lane)
  unsigned int w[8];
#pragma unroll
  for (int j = 0; j < 8; ++j)
    w[j] = (unsigned)f2bf(v[2 * j]) | ((unsigned)f2bf(v[2 * j + 1]) << 16);
  uint4* dst = (uint4*)(xbf + (size_t)n * DIM + lane * 16);
  dst[0] = make_uint4(w[0], w[1], w[2], w[3]);
  dst[1] = make_uint4(w[4], w[5], w[6], w[7]);

  double lg[NEXP];
#pragma unroll
  for (int e = 0; e < NEXP; ++e) {
    const float4* wp = (const float4*)(rw + (e << 10) + (lane << 4));
    float wv[16];
#pragma unroll
    for (int i = 0; i < 4; ++i) *(float4*)&wv[i * 4] = wp[i];
    double a = 0.0;
#pragma unroll
    for (int j = 0; j < 16; ++j) a += (double)v[j] * (double)wv[j];
#pragma unroll
    for (int off = 32; off > 0; off >>= 1) a += __shfl_down(a, off);
    lg[e] = a;
  }
  if (lane == 0) {
    int be = 0;
    double bv = lg[0] + (double)rb[0];
#pragma unroll
    for (int e = 1; e < NEXP; ++e) {
      double l = lg[e] + (double)rb[e];
      if (l > bv) { bv = l; be = e; }   // strict > keeps first index on ties (np.argmax)
    }
    int pos = atomicAdd(&counts[be], 1);
    tok[(be << 14) + pos] = n;
  }
}

// Grouped GEMM: C[m, o] = sum_d Xg[m, d] * W[o, d]  (both K-contiguous, "B^T" form)
// 128x128 tile, BK=64, 4 waves, mfma_f32_16x16x32_bf16.
// grid.x = expert*128 + token_tile, grid.y = output col tile (8).
__global__ __launch_bounds__(256, 2) void k_gemm(const unsigned short* __restrict__ xbf,
                                                 const unsigned short* __restrict__ wbf,
                                                 const float* __restrict__ eb,
                                                 const int* __restrict__ counts,
                                                 const int* __restrict__ tokall,
                                                 float* __restrict__ out) {
  const int e = blockIdx.x >> 7;
  const int t = blockIdx.x & 127;
  const int c = counts[e];
  if (t * 128 >= c) return;
  const int n0 = blockIdx.y << 7;
  const int* tok = tokall + (e << 14);
  const int tid = threadIdx.x;
  const int lane = tid & 63;
  const int wave = tid >> 6;

  __shared__ unsigned short As[128 * 64];  // 16 KB, row stride 128 B, chunk-swizzled
  __shared__ unsigned short Bs[128 * 64];

  // Staging: 4 calls of (32 rows x 8 chunks of 16B). LDS dest is linear
  // (global_load_lds requires it); swizzle applied on the GLOBAL source side:
  // physical chunk p at row r holds logical chunk p ^ (r & 7).
  const int prow = tid >> 3;
  const int pchk = tid & 7;
  size_t asrc[4], bsrc[4];
  const unsigned short* wb = wbf + ((size_t)e << 20);
#pragma unroll
  for (int s = 0; s < 4; ++s) {
    int row = s * 32 + prow;
    int m = t * 128 + row;
    int g = tok[(m < c) ? m : 0];          // pad rows replay token 0 (stores guarded)
    int l = pchk ^ (row & 7);
    asrc[s] = (size_t)g * DIM + (size_t)l * 8;
    bsrc[s] = (size_t)(n0 + row) * DIM + (size_t)l * 8;
  }

  f32x4 acc[4][4] = {};
  const int wr = wave >> 1, wc = wave & 1;

  // LDS read offsets (elements). A-frag: lane holds A[row = lane&15][k = (lane>>4)*8 + j].
  int aoff[2][4], boff[2][4];
#pragma unroll
  for (int h = 0; h < 2; ++h)
#pragma unroll
    for (int m = 0; m < 4; ++m) {
      int row = wr * 64 + m * 16 + (lane & 15);
      int p = (h * 4 + (lane >> 4)) ^ (row & 7);
      aoff[h][m] = row * 64 + p * 8;
      int rowb = wc * 64 + m * 16 + (lane & 15);
      int pb = (h * 4 + (lane >> 4)) ^ (rowb & 7);
      boff[h][m] = rowb * 64 + pb * 8;
    }

  for (int k0 = 0; k0 < DIM; k0 += 64) {
#pragma unroll
    for (int s = 0; s < 4; ++s) {
      __builtin_amdgcn_global_load_lds(
          (const __attribute__((address_space(1))) unsigned int*)(xbf + asrc[s] + k0),
          (__attribute__((address_space(3))) unsigned int*)(&As[s * 2048 + wave * 512]),
          16, 0, 0);
      __builtin_amdgcn_global_load_lds(
          (const __attribute__((address_space(1))) unsigned int*)(wb + bsrc[s] + k0),
          (__attribute__((address_space(3))) unsigned int*)(&Bs[s * 2048 + wave * 512]),
          16, 0, 0);
    }
    __syncthreads();
#pragma unroll
    for (int h = 0; h < 2; ++h) {
      bf16x8 af[4], bfr[4];
#pragma unroll
      for (int m = 0; m < 4; ++m) af[m] = *(const bf16x8*)&As[aoff[h][m]];
#pragma unroll
      for (int n = 0; n < 4; ++n) bfr[n] = *(const bf16x8*)&Bs[boff[h][n]];
#pragma unroll
      for (int m = 0; m < 4; ++m)
#pragma unroll
        for (int n = 0; n < 4; ++n)
          acc[m][n] = __builtin_amdgcn_mfma_f32_16x16x32_bf16(af[m], bfr[n], acc[m][n], 0, 0, 0);
    }
    __syncthreads();
  }

  // Epilogue: C/D layout col = lane&15, row = (lane>>4)*4 + reg. Add bias, scatter to out[token].
  const int colb = n0 + wc * 64 + (lane & 15);
  float bias[4];
#pragma unroll
  for (int n = 0; n < 4; ++n) bias[n] = eb[(e << 10) + colb + n * 16];
#pragma unroll
  for (int m = 0; m < 4; ++m) {
    int rbase = t * 128 + wr * 64 + m * 16 + ((lane >> 4) << 2);
#pragma unroll
    for (int r = 0; r < 4; ++r) {
      int mm = rbase + r;
      if (mm < c) {
        int g = tok[mm];
        float* op = out + ((size_t)g << 10);
#pragma unroll
        for (int n = 0; n < 4; ++n) op[colb + n * 16] = acc[m][n][r] + bias[n];
      }
    }
  }
}

extern "C" void kernel_launch(void* const* d_in, const int* in_sizes, int n_in,
                              void* d_out, int out_size, void* d_ws, size_t ws_size,
                              hipStream_t stream) {
  const float* x  = (const float*)d_in[0];
  const float* rw = (const float*)d_in[1];
  const float* rb = (const float*)d_in[2];
  const float* ew = (const float*)d_in[3];
  const float* eb = (const float*)d_in[4];
  float* out = (float*)d_out;

  char* ws = (char*)d_ws;
  unsigned short* wbf = (unsigned short*)ws;                       // 16 MB
  unsigned short* xbf = (unsigned short*)(ws + (16u << 20));       // 32 MB
  int* tok    = (int*)(ws + (48u << 20));                          // 512 KB
  int* counts = (int*)(ws + (48u << 20) + (1u << 19));             // 32 B

  k_init<<<1, 64, 0, stream>>>(counts);
  k_convw<<<4096, 256, 0, stream>>>(ew, wbf);                       // 8M elems / 8 per thread
  k_router<<<NTOK / 4, 256, 0, stream>>>(x, rw, rb, xbf, counts, tok);
  k_gemm<<<dim3(NEXP * 128, DIM / 128), 256, 0, stream>>>(xbf, wbf, eb, counts, tok, out);
}